// Round 6
// baseline (155.699 us; speedup 1.0000x reference)
//
#include <hip/hip_runtime.h>
#include <hip/hip_bf16.h>

#define HW 4096  // 64*64 spatial

// Static device scratch (24 MiB): qkv[m][b][o][h][w] fp32, m in {0:q,1:k,2:v}.
// Fully rewritten by qkv_proj before attn reads it on every launch -> graph-safe.
__device__ float g_qkv[3 * 8 * 64 * HW];

// One block per (b,h); thread = (w = t&63, ou = t>>6). Weights come from SMEM
// (wave-uniform addresses via readfirstlane -> s_load_dwordx4), x from LDS in
// 4-channel blocks (ds_read2_b32 pairs, conflict-free). 16 independent
// accumulators per matrix -> no dependent-chain stall (R5: single acc chain +
// xr[64] demotion = 54 us, VALUBusy 17%). VALU floor ~5.1 us.
__global__ __launch_bounds__(256) void qkv_proj(
    const float* __restrict__ x,
    const float* __restrict__ wq,
    const float* __restrict__ wk,
    const float* __restrict__ wv)
{
    __shared__ float xs[64][64];      // [c][w] 16 KB
    const int t = threadIdx.x;
    const int b = blockIdx.x >> 6;
    const int h = blockIdx.x & 63;

    const float* xrow = x + (size_t)b * 64 * HW + (size_t)h * 64;
    for (int i = t; i < 64 * 64; i += 256) {
        int c = i >> 6, w = i & 63;
        xs[c][w] = xrow[(size_t)c * HW + w];
    }
    __syncthreads();

    const int w = t & 63;
    const int ou = __builtin_amdgcn_readfirstlane(t >> 6);  // wave-uniform 0..3

    const float* __restrict__ mats[3] = { wq, wk, wv };
    #pragma unroll 1
    for (int m = 0; m < 3; ++m) {
        const float* __restrict__ wg = mats[m];
        float acc[16];
        #pragma unroll
        for (int oi = 0; oi < 16; ++oi) acc[oi] = 0.f;

        #pragma unroll 2
        for (int cb = 0; cb < 16; ++cb) {
            // 4 x values live at a time; lane-stride-1 LDS reads, 2-way alias = free
            float x0 = xs[cb * 4 + 0][w];
            float x1 = xs[cb * 4 + 1][w];
            float x2 = xs[cb * 4 + 2][w];
            float x3 = xs[cb * 4 + 3][w];
            #pragma unroll
            for (int oi = 0; oi < 16; ++oi) {
                const float* wr = wg + ((oi * 4 + ou) << 6) + cb * 4;  // uniform -> s_load_dwordx4
                acc[oi] = fmaf(wr[3], x3, fmaf(wr[2], x2, fmaf(wr[1], x1, fmaf(wr[0], x0, acc[oi]))));
            }
        }
        float* op = g_qkv + ((size_t)m * 8 + b) * (64 * HW) + (size_t)h * 64 + w;
        #pragma unroll
        for (int oi = 0; oi < 16; ++oi)
            op[(size_t)(oi * 4 + ou) * HW] = acc[oi];
    }
}

// One block per (b,o): 7x7 local attention, k/v halo in LDS.
// rel_w/rel_h are dead (constant along the 49-entry softmax axis -> cancel by
// shift-invariance). Zero padding + 1x1 conv => k=v=0 outside; logit q*0=0
// still participates. Layout kv[r][0..69]=k, kv[r][70..139]=v: the per-tap
// k,v pair merges to ds_read2_b32 (offsets 0/280B) and lanes span all 32
// banks (2-way alias = free), unlike R5's float2 interleave (4-way, 1.58x).
__global__ __launch_bounds__(256) void attn(float* __restrict__ out)
{
    __shared__ float kv[70][140];   // 39.2 KB
    const int t = threadIdx.x;
    const int b = blockIdx.x >> 6;
    const int o = blockIdx.x & 63;

    const float* qb = g_qkv + ((size_t)(0 * 8 + b) * 64 + o) * HW;
    const float* kb = g_qkv + ((size_t)(1 * 8 + b) * 64 + o) * HW;
    const float* vb = g_qkv + ((size_t)(2 * 8 + b) * 64 + o) * HW;

    for (int i = t; i < 70 * 70; i += 256) {
        int r = i / 70, c = i - r * 70;
        int gh = r - 3, gw = c - 3;
        float kk = 0.f, vv = 0.f;
        if ((unsigned)gh < 64u && (unsigned)gw < 64u) {
            kk = kb[gh * 64 + gw];
            vv = vb[gh * 64 + gw];
        }
        kv[r][c] = kk;
        kv[r][70 + c] = vv;
    }
    __syncthreads();

    const int w = t & 63;
    const int band = t >> 6;          // 0..3
    float* ob = out + ((size_t)(b * 64 + o)) * HW;

    #pragma unroll 1                  // small body x4: I-cache friendly
    for (int pass = 0; pass < 4; ++pass) {
        const int r0 = pass * 16 + band * 4;   // 4 vertically adjacent pixel rows
        float qv[4], den[4], num[4];
        #pragma unroll
        for (int j = 0; j < 4; ++j) {
            qv[j] = qb[(r0 + j) * 64 + w];
            den[j] = 0.f; num[j] = 0.f;
        }
        // halo rows r0..r0+9; pixel j uses halo row r0+rr iff 0 <= rr-j < 7
        #pragma unroll
        for (int rr = 0; rr < 10; ++rr) {
            #pragma unroll
            for (int dj = 0; dj < 7; ++dj) {
                float kk = kv[r0 + rr][w + dj];        // merge -> ds_read2_b32
                float vv = kv[r0 + rr][70 + w + dj];
                #pragma unroll
                for (int j = 0; j < 4; ++j) {
                    if (rr - j >= 0 && rr - j < 7) {   // compile-time predicate
                        float e = __expf(qv[j] * kk);  // |logit| < ~25: no max pass needed
                        den[j] += e;
                        num[j] = fmaf(e, vv, num[j]);
                    }
                }
            }
        }
        #pragma unroll
        for (int j = 0; j < 4; ++j)
            ob[(r0 + j) * 64 + w] = num[j] / den[j];
    }
}

extern "C" void kernel_launch(void* const* d_in, const int* in_sizes, int n_in,
                              void* d_out, int out_size, void* d_ws, size_t ws_size,
                              hipStream_t stream)
{
    // d_in: 0=x, 1=wq, 2=wk, 3=wv (fp32), 4=rel_w, 5=rel_h (dead: softmax
    // shift-invariance), 6=kernel_size(7), 7=padding(3) hardcoded.
    qkv_proj<<<dim3(512), dim3(256), 0, stream>>>(
        (const float*)d_in[0], (const float*)d_in[1],
        (const float*)d_in[2], (const float*)d_in[3]);
    attn<<<dim3(512), dim3(256), 0, stream>>>((float*)d_out);
}

// Round 7
// 152.102 us; speedup vs baseline: 1.0237x; 1.0237x over previous
//
#include <hip/hip_runtime.h>
#include <hip/hip_bf16.h>

#define HW 4096  // 64*64 spatial

// Static device scratch (24 MiB): qkv[m][b][o][h][w] fp32, m in {0:q,1:k,2:v}.
// Fully rewritten by qkv_proj before attn reads it on every launch -> graph-safe.
__device__ float g_qkv[3 * 8 * 64 * HW];

// One block per (b,h). Register-tiled matmul: thread = (to,tw) computes a
// 4o x 4w tile for all 3 matrices (48 accumulators). Both operands staged in
// LDS (W transposed so the o-dimension is contiguous); per c-step the inner
// loop is 4x ds_read_b128 + 48 v_fmac with pure register operands — no
// global/scalar loads in the hot loop (R5/R6 died on weight-load latency at
// 2 waves/SIMD: 54/64.5 us, VALUBusy 17-21%). LDS-traffic floor ~7 us.
__global__ __launch_bounds__(256, 2) void qkv_proj(
    const float* __restrict__ x,
    const float* __restrict__ wq,
    const float* __restrict__ wk,
    const float* __restrict__ wv)
{
    __shared__ float xs[64][64];      // [c][w] 16 KB
    __shared__ float wt[3][64][65];   // [m][c][o], +1 pad: transpose-write 2-way only
    const int t = threadIdx.x;
    const int b = blockIdx.x >> 6;
    const int h = blockIdx.x & 63;

    {   // stage weights transposed: read row-major coalesced, write [c][o]
        const float* __restrict__ mats[3] = { wq, wk, wv };
        #pragma unroll
        for (int m = 0; m < 3; ++m)
            for (int i = t; i < 4096; i += 256) {
                int o = i >> 6, c = i & 63;
                wt[m][c][o] = mats[m][i];
            }
    }
    {   // stage x[b,:,h,:] -> xs[c][w]
        const float* xrow = x + (size_t)b * 64 * HW + (size_t)h * 64;
        for (int i = t; i < 4096; i += 256) {
            int c = i >> 6, w = i & 63;
            xs[c][w] = xrow[(size_t)c * HW + w];
        }
    }
    __syncthreads();

    const int tw = t & 15;            // w-quad index
    const int to = t >> 4;            // o-quad index
    const int w0 = tw * 4, o0 = to * 4;

    float acc[3][16];
    #pragma unroll
    for (int m = 0; m < 3; ++m)
        #pragma unroll
        for (int i = 0; i < 16; ++i) acc[m][i] = 0.f;

    #pragma unroll 2
    for (int c = 0; c < 64; ++c) {
        const float4 xv = *(const float4*)&xs[c][w0];          // b128, 2-way = free
        #pragma unroll
        for (int m = 0; m < 3; ++m) {
            const float4 wv4 = *(const float4*)&wt[m][c][o0];  // b128, broadcast quads
            const float wa[4] = { wv4.x, wv4.y, wv4.z, wv4.w };
            const float xa[4] = { xv.x, xv.y, xv.z, xv.w };
            #pragma unroll
            for (int oi = 0; oi < 4; ++oi)
                #pragma unroll
                for (int wi = 0; wi < 4; ++wi)
                    acc[m][oi * 4 + wi] = fmaf(wa[oi], xa[wi], acc[m][oi * 4 + wi]);
        }
    }

    #pragma unroll
    for (int m = 0; m < 3; ++m) {
        float* op = g_qkv + ((size_t)m * 8 + b) * (64 * HW) + (size_t)h * 64 + w0;
        #pragma unroll
        for (int oi = 0; oi < 4; ++oi) {
            float4 v = { acc[m][oi * 4 + 0], acc[m][oi * 4 + 1],
                         acc[m][oi * 4 + 2], acc[m][oi * 4 + 3] };
            *(float4*)&op[(size_t)(o0 + oi) * HW] = v;         // 256B segments, coalesced
        }
    }
}

// One block per (b, o, quarter): 7x7 local attention on a 16-row strip
// (22-row halo in LDS, 12.3 KB -> 8 blocks/CU = 8 waves/SIMD, vs R6's 2).
// rel_w/rel_h are dead: constant along the 49-entry softmax axis -> cancel
// (shift-invariance). Zero padding + 1x1 conv => k=v=0 outside; logit q*0=0
// still participates. q pre-scaled by log2(e): per tap = v_mul + v_exp_f32.
// k at kv[r][0..69], v at kv[r][70..139] -> per-tap pair = ds_read2_b32,
// lanes span all banks (2-way = free).
__global__ __launch_bounds__(256) void attn(float* __restrict__ out)
{
    __shared__ float kv[22][140];     // 12.3 KB
    const int t = threadIdx.x;
    const int blk = blockIdx.x;
    const int quarter = blk & 3;
    const int bo = blk >> 2;
    const int b = bo >> 6, o = bo & 63;
    const int r0 = quarter * 16;

    const float* qb = g_qkv + ((size_t)(0 * 8 + b) * 64 + o) * HW;
    const float* kb = g_qkv + ((size_t)(1 * 8 + b) * 64 + o) * HW;
    const float* vb = g_qkv + ((size_t)(2 * 8 + b) * 64 + o) * HW;

    for (int i = t; i < 22 * 70; i += 256) {
        int r = i / 70, c = i - r * 70;
        int gh = r0 + r - 3, gw = c - 3;
        float kk = 0.f, vv = 0.f;
        if ((unsigned)gh < 64u && (unsigned)gw < 64u) {
            kk = kb[gh * 64 + gw];
            vv = vb[gh * 64 + gw];
        }
        kv[r][c] = kk;
        kv[r][70 + c] = vv;
    }
    __syncthreads();

    const int w = t & 63;
    const int band = t >> 6;          // 0..3 -> 4 pixel rows each
    const int rl = band * 4;          // local pixel row base
    const float LOG2E = 1.4426950408889634f;

    float qv[4], den[4], num[4];
    #pragma unroll
    for (int j = 0; j < 4; ++j) {
        qv[j] = qb[(r0 + rl + j) * 64 + w] * LOG2E;
        den[j] = 0.f; num[j] = 0.f;
    }
    // halo local rows rl..rl+9; pixel j uses row rl+rr iff 0 <= rr-j < 7
    #pragma unroll
    for (int rr = 0; rr < 10; ++rr) {
        #pragma unroll
        for (int dj = 0; dj < 7; ++dj) {
            float kk = kv[rl + rr][w + dj];        // pair -> ds_read2_b32
            float vv = kv[rl + rr][70 + w + dj];
            #pragma unroll
            for (int j = 0; j < 4; ++j) {
                if (rr - j >= 0 && rr - j < 7) {   // compile-time predicate
                    float e = exp2f(qv[j] * kk);   // native v_exp_f32
                    den[j] += e;
                    num[j] = fmaf(e, vv, num[j]);
                }
            }
        }
    }
    float* ob = out + ((size_t)(b * 64 + o)) * HW;
    #pragma unroll
    for (int j = 0; j < 4; ++j)
        ob[(r0 + rl + j) * 64 + w] = num[j] / den[j];
}

extern "C" void kernel_launch(void* const* d_in, const int* in_sizes, int n_in,
                              void* d_out, int out_size, void* d_ws, size_t ws_size,
                              hipStream_t stream)
{
    // d_in: 0=x, 1=wq, 2=wk, 3=wv (fp32), 4=rel_w, 5=rel_h (dead: softmax
    // shift-invariance), 6=kernel_size(7), 7=padding(3) hardcoded.
    qkv_proj<<<dim3(512), dim3(256), 0, stream>>>(
        (const float*)d_in[0], (const float*)d_in[1],
        (const float*)d_in[2], (const float*)d_in[3]);
    attn<<<dim3(2048), dim3(256), 0, stream>>>((float*)d_out);
}

// Round 9
// 115.864 us; speedup vs baseline: 1.3438x; 1.3128x over previous
//
#include <hip/hip_runtime.h>

#define HW 4096  // 64*64 spatial

// Static device scratch (24 MiB): qkv[m][b][o][h][w] fp32, m in {0:q,1:k,2:v}.
// Fully rewritten by qkv_proj before attn reads it on every launch -> graph-safe.
__device__ float g_qkv[3 * 8 * 64 * HW];

#if __has_builtin(__builtin_amdgcn_exp2f)
#define QSCALE 1.4426950408889634f            // prescale q by log2(e); exp2 is native v_exp_f32
__device__ __forceinline__ float fexp(float l) { return __builtin_amdgcn_exp2f(l); }
#else
#define QSCALE 1.0f
__device__ __forceinline__ float fexp(float l) { return __expf(l); }
#endif

// One block per (b,h). Register-tiled: thread = (to,tw) computes 4o x 4w for all
// 3 matrices (48 independent accumulators -> no dep-chain stall). x via aligned
// float4 LDS reads (2-way alias = free). W rows stride 65 dwords + SCALAR reads:
// o-group bank step = 4*65 mod 32 = 4 -> 2-way = free. (16B-aligned float4 W
// reads are impossible without >=8-way conflicts: 4-row o0 step = 16s mod 32.)
// Effective clock ~0.5 GHz (DVFS floor, 10ms idle between bursts): VALU issue
// floor ~24.6 us; R4-R7 all ~45 us = stall-dominated at 2 waves/SIMD.
__global__ __launch_bounds__(256, 2) void qkv_proj(
    const float* __restrict__ x,
    const float* __restrict__ wq,
    const float* __restrict__ wk,
    const float* __restrict__ wv)
{
    __shared__ float xs[64][64];      // [c][w] 16 KB
    __shared__ float wl[3][64][65];   // [m][o][c], stride 65
    const int t = threadIdx.x;
    const int b = blockIdx.x >> 6;
    const int h = blockIdx.x & 63;

    {
        const float* __restrict__ mats[3] = { wq, wk, wv };
        #pragma unroll
        for (int m = 0; m < 3; ++m)
            for (int i = t; i < 4096; i += 256) {
                int o = i >> 6, c = i & 63;
                wl[m][o][c] = mats[m][i];          // straight copy, consecutive-c writes
            }
        const float* xrow = x + (size_t)b * 64 * HW + (size_t)h * 64;
        for (int i = t; i < 4096; i += 256) {
            int c = i >> 6, w = i & 63;
            xs[c][w] = xrow[(size_t)c * HW + w];
        }
    }
    __syncthreads();

    const int w0 = (t & 15) * 4;                   // w-quad
    const int o0 = (t >> 4) * 4;                   // o-quad
    float acc[3][16];
    #pragma unroll
    for (int m = 0; m < 3; ++m)
        #pragma unroll
        for (int i = 0; i < 16; ++i) acc[m][i] = 0.f;

    #pragma unroll 4
    for (int cq = 0; cq < 16; ++cq) {
        const int c0 = cq * 4;
        float xa[4][4];                            // [ci][wi]
        #pragma unroll
        for (int ci = 0; ci < 4; ++ci)
            *(float4*)&xa[ci][0] = *(const float4*)&xs[c0 + ci][w0];   // aligned b128
        #pragma unroll
        for (int m = 0; m < 3; ++m)
            #pragma unroll
            for (int oi = 0; oi < 4; ++oi) {
                #pragma unroll
                for (int ci = 0; ci < 4; ++ci) {
                    const float wv1 = wl[m][o0 + oi][c0 + ci];  // scalar b32, 2-way = free
                    #pragma unroll
                    for (int wi = 0; wi < 4; ++wi)
                        acc[m][oi * 4 + wi] = fmaf(wv1, xa[ci][wi], acc[m][oi * 4 + wi]);
                }
            }
    }

    #pragma unroll
    for (int m = 0; m < 3; ++m) {
        float* op = g_qkv + ((size_t)m * 8 + b) * (64 * HW) + (size_t)h * 64 + w0;
        #pragma unroll
        for (int oi = 0; oi < 4; ++oi) {
            float4 v = { acc[m][oi * 4 + 0], acc[m][oi * 4 + 1],
                         acc[m][oi * 4 + 2], acc[m][oi * 4 + 3] };
            *(float4*)&op[(size_t)(o0 + oi) * HW] = v;         // 256B coalesced segments
        }
    }
}

// One block per (b,o): 7x7 local attention, full 70x70 k/v halo in LDS.
// Thread owns a 4x4 PIXEL TILE: window union = 10x10 taps, 200 LDS dwords per
// 16 pixels (12.5/px vs R4's 35/px). exp count/thread (784) is the VALU floor
// (~27 us at 0.5 GHz) — unchanged, but stalls shrink with 2.8x fewer LDS ops.
// rel_w/rel_h dead (constant along 49-entry softmax axis -> shift-invariance).
// Zero padding + 1x1 conv => k=v=0 outside; logit q*0=0 still participates.
// k at kv[r][0..69], v at kv[r][70..139]: pair -> ds_read2_b32 offsets 0/70.
__global__ __launch_bounds__(256, 2) void attn(float* __restrict__ out)
{
    __shared__ float kv[70][140];     // 39.2 KB
    const int t = threadIdx.x;
    const int b = blockIdx.x >> 6;
    const int o = blockIdx.x & 63;

    const float* qb = g_qkv + ((size_t)(0 * 8 + b) * 64 + o) * HW;
    const float* kb = g_qkv + ((size_t)(1 * 8 + b) * 64 + o) * HW;
    const float* vb = g_qkv + ((size_t)(2 * 8 + b) * 64 + o) * HW;

    for (int i = t; i < 70 * 70; i += 256) {
        int r = i / 70, c = i - r * 70;
        int gh = r - 3, gw = c - 3;
        float kk = 0.f, vv = 0.f;
        if ((unsigned)gh < 64u && (unsigned)gw < 64u) {
            kk = kb[gh * 64 + gw];
            vv = vb[gh * 64 + gw];
        }
        kv[r][c] = kk;
        kv[r][70 + c] = vv;
    }
    __syncthreads();

    const int r0 = (t >> 4) * 4;      // pixel-tile row base (0..60)
    const int c0 = (t & 15) * 4;      // pixel-tile col base (0..60)

    float qv[16], den[16], num[16];
    #pragma unroll
    for (int i = 0; i < 4; ++i) {
        float4 q4 = *(const float4*)&qb[(r0 + i) * 64 + c0];
        qv[i * 4 + 0] = q4.x * QSCALE; qv[i * 4 + 1] = q4.y * QSCALE;
        qv[i * 4 + 2] = q4.z * QSCALE; qv[i * 4 + 3] = q4.w * QSCALE;
    }
    #pragma unroll
    for (int i = 0; i < 16; ++i) { den[i] = 0.f; num[i] = 0.f; }

    // halo rows r0..r0+9, cols c0..c0+9; pixel (i,j) active iff rr-i,cc-j in [0,7)
    #pragma unroll
    for (int rr = 0; rr < 10; ++rr) {
        #pragma unroll
        for (int cc = 0; cc < 10; ++cc) {
            const float kk = kv[r0 + rr][c0 + cc];        // pair -> ds_read2_b32
            const float vv = kv[r0 + rr][70 + c0 + cc];
            #pragma unroll
            for (int i = 0; i < 4; ++i) {
                if (rr - i >= 0 && rr - i < 7) {          // compile-time predicates
                    #pragma unroll
                    for (int j = 0; j < 4; ++j) {
                        if (cc - j >= 0 && cc - j < 7) {
                            float e = fexp(qv[i * 4 + j] * kk);
                            den[i * 4 + j] += e;
                            num[i * 4 + j] = fmaf(e, vv, num[i * 4 + j]);
                        }
                    }
                }
            }
        }
    }

    float* ob = out + ((size_t)(b * 64 + o)) * HW;
    #pragma unroll
    for (int i = 0; i < 4; ++i) {
        float4 v = { num[i * 4 + 0] / den[i * 4 + 0], num[i * 4 + 1] / den[i * 4 + 1],
                     num[i * 4 + 2] / den[i * 4 + 2], num[i * 4 + 3] / den[i * 4 + 3] };
        *(float4*)&ob[(r0 + i) * 64 + c0] = v;
    }
}

extern "C" void kernel_launch(void* const* d_in, const int* in_sizes, int n_in,
                              void* d_out, int out_size, void* d_ws, size_t ws_size,
                              hipStream_t stream)
{
    // d_in: 0=x, 1=wq, 2=wk, 3=wv (fp32), 4=rel_w, 5=rel_h (dead: softmax
    // shift-invariance), 6=kernel_size(7), 7=padding(3) hardcoded.
    qkv_proj<<<dim3(512), dim3(256), 0, stream>>>(
        (const float*)d_in[0], (const float*)d_in[1],
        (const float*)d_in[2], (const float*)d_in[3]);
    attn<<<dim3(512), dim3(256), 0, stream>>>((float*)d_out);
}